// Round 9
// baseline (265.945 us; speedup 1.0000x reference)
//
#include <hip/hip_runtime.h>
#include <hip/hip_bf16.h>
#include <cstdint>

typedef __bf16 bf16;
typedef __bf16 bf16x4 __attribute__((ext_vector_type(4)));
typedef __bf16 bf16x8 __attribute__((ext_vector_type(8)));
typedef float f32x4 __attribute__((ext_vector_type(4)));

#define B_  4
#define T_  2048
#define C_  768
#define NH_ 12
#define HD_ 64
#define BH_ (B_ * NH_)

__device__ __forceinline__ f32x4 mfma16(bf16x8 a, bf16x8 b, f32x4 c) {
  return __builtin_amdgcn_mfma_f32_16x16x32_bf16(a, b, c, 0, 0, 0);
}

// async global->LDS, 16B per lane; lds dst must be wave-uniform base (HW adds lane*16)
__device__ __forceinline__ void gload16(const bf16* src, bf16* dst) {
  __builtin_amdgcn_global_load_lds(
      (const __attribute__((address_space(1))) unsigned int*)src,
      (__attribute__((address_space(3))) unsigned int*)dst, 16, 0, 0);
}

// ---------------------------------------------------------------- convert (x)
__global__ __launch_bounds__(256) void cvt_kernel(const float* __restrict__ in,
                                                  bf16* __restrict__ out, int n4) {
  int i = blockIdx.x * blockDim.x + threadIdx.x;
  if (i < n4) {
    float4 v = reinterpret_cast<const float4*>(in)[i];
    bf16x4 o;
    o[0] = (bf16)v.x; o[1] = (bf16)v.y; o[2] = (bf16)v.z; o[3] = (bf16)v.w;
    reinterpret_cast<bf16x4*>(out)[i] = o;
  }
}

// ------------------------------------------- weight transpose+convert: WT[n][k] = W[k][n]
__global__ __launch_bounds__(256) void wtr_kernel(const float* __restrict__ W,
                                                  bf16* __restrict__ WT, int K, int N) {
  __shared__ bf16 t[64][72];
  const int tid = threadIdx.x;
  const int k0 = blockIdx.x * 64, n0 = blockIdx.y * 64;
  {
    const int r = tid >> 2, cg = (tid & 3) * 16;
    const float* src = W + (size_t)(k0 + r) * N + n0 + cg;
    float4 a0 = reinterpret_cast<const float4*>(src)[0];
    float4 a1 = reinterpret_cast<const float4*>(src)[1];
    float4 a2 = reinterpret_cast<const float4*>(src)[2];
    float4 a3 = reinterpret_cast<const float4*>(src)[3];
    bf16x8 lo, hi;
    lo[0]=(bf16)a0.x; lo[1]=(bf16)a0.y; lo[2]=(bf16)a0.z; lo[3]=(bf16)a0.w;
    lo[4]=(bf16)a1.x; lo[5]=(bf16)a1.y; lo[6]=(bf16)a1.z; lo[7]=(bf16)a1.w;
    hi[0]=(bf16)a2.x; hi[1]=(bf16)a2.y; hi[2]=(bf16)a2.z; hi[3]=(bf16)a2.w;
    hi[4]=(bf16)a3.x; hi[5]=(bf16)a3.y; hi[6]=(bf16)a3.z; hi[7]=(bf16)a3.w;
    *reinterpret_cast<bf16x8*>(&t[r][cg]) = lo;
    *reinterpret_cast<bf16x8*>(&t[r][cg + 8]) = hi;
  }
  __syncthreads();
  {
    const int n = tid & 63, kg = (tid >> 6) * 16;
    bf16x8 o0, o1;
#pragma unroll
    for (int i = 0; i < 8; ++i) { o0[i] = t[kg + i][n]; o1[i] = t[kg + 8 + i][n]; }
    bf16* dst = WT + (size_t)(n0 + n) * K + k0 + kg;
    *reinterpret_cast<bf16x8*>(dst) = o0;
    *reinterpret_cast<bf16x8*>(dst + 8) = o1;
  }
}

// ---------------------------------------------------------------- GEMM (m97-style, BK=64)
// C[M,N] = A[M,K] @ B, BT is B transposed ([N][K]). Both bf16.
// EPI 0: scatter to Q/K/V bf16 (Q scaled by 0.125*log2e). EPI 1: fp32 out.
template <int EPI>
__global__ __launch_bounds__(256) void gemm_mfma(
    const bf16* __restrict__ A, const bf16* __restrict__ BT,
    const float* __restrict__ bias, int M, int N, int K,
    bf16* __restrict__ q, bf16* __restrict__ k_, bf16* __restrict__ v,
    float* __restrict__ out) {
  __shared__ bf16 AlF[128 * 64];   // [m][k] linear (global_load_lds dest)
  __shared__ bf16 BlF[128 * 64];   // [n][k] linear

  const int tid = threadIdx.x;
  const int wid = tid >> 6, lane = tid & 63;
  unsigned orig = blockIdx.y * gridDim.x + blockIdx.x;
  unsigned cpx = (gridDim.x * gridDim.y) >> 3;
  unsigned work = (orig & 7) * cpx + (orig >> 3);
  const int m0 = (work / gridDim.x) * 128, n0 = (work % gridDim.x) * 128;
  const int wm = (wid >> 1) * 64, wn = (wid & 1) * 64;
  const int r = lane & 15, g = lane >> 4;

  f32x4 acc[4][4] = {};

  const int l8 = lane >> 3;          // 0..7 row-within-issue
  const int c8 = (lane & 7) * 8;     // k-col group

  for (int k0 = 0; k0 < K; k0 += 64) {
    __syncthreads();
#pragma unroll
    for (int i = 0; i < 4; ++i) {
      int row = i * 32 + wid * 8 + l8;
      gload16(A  + (size_t)(m0 + row) * K + k0 + c8, AlF + (i * 32 + wid * 8) * 64);
      gload16(BT + (size_t)(n0 + row) * K + k0 + c8, BlF + (i * 32 + wid * 8) * 64);
    }
    __syncthreads();

#pragma unroll
    for (int kc = 0; kc < 2; ++kc) {
      bf16x8 bfr[4];
#pragma unroll
      for (int fn = 0; fn < 4; ++fn)
        bfr[fn] = *reinterpret_cast<bf16x8*>(&BlF[(wn + fn * 16 + r) * 64 + kc * 32 + g * 8]);
#pragma unroll
      for (int fm = 0; fm < 4; ++fm) {
        bf16x8 af = *reinterpret_cast<bf16x8*>(&AlF[(wm + fm * 16 + r) * 64 + kc * 32 + g * 8]);
#pragma unroll
        for (int fn = 0; fn < 4; ++fn)
          acc[fm][fn] = mfma16(af, bfr[fn], acc[fm][fn]);
      }
    }
  }

  // epilogue: C row = g*4+j, col = r  (verified m89/m91 layout)
#pragma unroll
  for (int fm = 0; fm < 4; ++fm)
#pragma unroll
    for (int fn = 0; fn < 4; ++fn)
#pragma unroll
      for (int j = 0; j < 4; ++j) {
        int m = m0 + wm + fm * 16 + g * 4 + j;
        int n = n0 + wn + fn * 16 + r;
        float val = acc[fm][fn][j] + bias[n];
        if (EPI == 0) {
          int b = m >> 11, t = m & 2047;
          bf16* dst; int c;
          if (n < 768)        { dst = q;  c = n;        val *= 0.180336881f; }  // 0.125*log2(e)
          else if (n < 1536)  { dst = k_; c = n - 768;  }
          else                { dst = v;  c = n - 1536; }
          int h = c >> 6, d = c & 63;
          dst[(((size_t)(b * NH_ + h)) * T_ + t) * HD_ + d] = (bf16)val;
        } else {
          out[(size_t)m * N + n] = val;
        }
      }
}

// ---------------------------------------------------------------- attention
// grid: (16, B*NH), XCD-swizzled. Block x processes tiles A=x and B=31-x (64 q-rows
// each) CONCURRENTLY sharing one KV stream: loop s=0..31-x; B computes every step,
// A only while s<=x. 33 compute-steps/block (uniform), <=32 stagings.
// Swapped QK^T: lane owns q = qt0 + r. exp2-domain softmax, defer-max thr 8.
__global__ __launch_bounds__(256) void attn_fwd(
    const bf16* __restrict__ Q, const bf16* __restrict__ K,
    const bf16* __restrict__ V, bf16* __restrict__ Y) {
  __shared__ bf16 Kl[64][72];          // [kv][d]
  __shared__ bf16 VtF[64 * 72];        // swizzled [d][kv]
  __shared__ bf16 Pl[4][2][16][72];    // per-wave, per-tile P buffer [qrow][kv]

  const int tid = threadIdx.x;
  const int wid = tid >> 6, lane = tid & 63;
  const int r = lane & 15, g = lane >> 4;

  // XCD swizzle: 768 blocks -> 96-work chunks per XCD (6 whole heads)
  unsigned orig = blockIdx.y * 16 + blockIdx.x;
  unsigned work = (orig & 7) * 96 + (orig >> 3);
  const int bx = work & 15;
  const int bh = work >> 4;
  const int bidx = bh / NH_, h = bh % NH_;

  const bf16* Qb = Q + (size_t)bh * T_ * HD_;
  const bf16* Kb = K + (size_t)bh * T_ * HD_;
  const bf16* Vb = V + (size_t)bh * T_ * HD_;

  const int krow = tid >> 3;          // 0..31
  const int kc8 = (tid & 7) * 8;

  const int tA = bx, tB = 31 - bx;
  const int qt0A = tA * 64 + wid * 16;
  const int qt0B = tB * 64 + wid * 16;

  bf16x8 qfA[2], qfB[2];
#pragma unroll
  for (int kc = 0; kc < 2; ++kc) {
    qfA[kc] = *reinterpret_cast<const bf16x8*>(Qb + (size_t)(qt0A + r) * HD_ + kc * 32 + g * 8);
    qfB[kc] = *reinterpret_cast<const bf16x8*>(Qb + (size_t)(qt0B + r) * HD_ + kc * 32 + g * 8);
  }

  float mA = -INFINITY, lA = 0.f, mB = -INFINITY, lB = 0.f;
  f32x4 oA[4] = {}, oB[4] = {};

  const int nsteps = tB + 1;
  for (int s = 0; s < nsteps; ++s) {
    const int kv0 = s * 64;
    __syncthreads();
#pragma unroll
    for (int p = 0; p < 2; ++p) {
      int row = p * 32 + krow;
      bf16x8 kv8 = *reinterpret_cast<const bf16x8*>(Kb + (size_t)(kv0 + row) * HD_ + kc8);
      *reinterpret_cast<bf16x8*>(&Kl[row][kc8]) = kv8;
      bf16x8 vv8 = *reinterpret_cast<const bf16x8*>(Vb + (size_t)(kv0 + row) * HD_ + kc8);
      int xorb = (((row >> 3) ^ (tid & 7)) << 3) + (row & 7);
#pragma unroll
      for (int j = 0; j < 8; ++j) VtF[(kc8 + j) * 72 + xorb] = vv8[j];
    }
    __syncthreads();

    // one tile's QK^T -> softmax -> PV (shared staged K/V)
    auto process = [&](const bf16x8 (&qf)[2], float& m_st, float& l_p, f32x4 (&o)[4],
                       bf16* PlW, int qt0, bool diag) {
      f32x4 s4[4] = {};
      __builtin_amdgcn_s_setprio(1);
#pragma unroll
      for (int cb = 0; cb < 4; ++cb)
#pragma unroll
        for (int kc = 0; kc < 2; ++kc) {
          bf16x8 kf = *reinterpret_cast<bf16x8*>(&Kl[cb * 16 + r][kc * 32 + g * 8]);
          s4[cb] = mfma16(kf, qf[kc], s4[cb]);
        }
      __builtin_amdgcn_s_setprio(0);

      if (diag) {
#pragma unroll
        for (int cb = 0; cb < 4; ++cb)
#pragma unroll
          for (int j = 0; j < 4; ++j)
            if (kv0 + cb * 16 + g * 4 + j > qt0 + r) s4[cb][j] = -INFINITY;
      }

      float pmax = fmaxf(
          fmaxf(fmaxf(fmaxf(s4[0][0], s4[0][1]), fmaxf(s4[0][2], s4[0][3])),
                fmaxf(fmaxf(s4[1][0], s4[1][1]), fmaxf(s4[1][2], s4[1][3]))),
          fmaxf(fmaxf(fmaxf(s4[2][0], s4[2][1]), fmaxf(s4[2][2], s4[2][3])),
                fmaxf(fmaxf(s4[3][0], s4[3][1]), fmaxf(s4[3][2], s4[3][3]))));
      pmax = fmaxf(pmax, __shfl_xor(pmax, 16));
      pmax = fmaxf(pmax, __shfl_xor(pmax, 32));

      if (!__all(pmax - m_st <= 8.0f)) {
        float sc = exp2f(m_st - pmax);
        m_st = pmax;
        l_p *= sc;
        float sc0 = __shfl(sc, g * 4 + 0);
        float sc1 = __shfl(sc, g * 4 + 1);
        float sc2 = __shfl(sc, g * 4 + 2);
        float sc3 = __shfl(sc, g * 4 + 3);
#pragma unroll
        for (int dn = 0; dn < 4; ++dn) {
          o[dn][0] *= sc0; o[dn][1] *= sc1; o[dn][2] *= sc2; o[dn][3] *= sc3;
        }
      }

      float sum = 0.f;
#pragma unroll
      for (int cb = 0; cb < 4; ++cb) {
        bf16x4 pw;
#pragma unroll
        for (int j = 0; j < 4; ++j) {
          float pv = exp2f(s4[cb][j] - m_st);
          sum += pv;
          pw[j] = (bf16)pv;
        }
        *reinterpret_cast<bf16x4*>(&PlW[r * 72 + cb * 16 + g * 4]) = pw;
      }
      l_p += sum;

      __builtin_amdgcn_s_setprio(1);
#pragma unroll
      for (int kc = 0; kc < 2; ++kc) {
        bf16x8 pf = *reinterpret_cast<bf16x8*>(&PlW[r * 72 + kc * 32 + g * 8]);
#pragma unroll
        for (int dn = 0; dn < 4; ++dn) {
          int d = dn * 16 + r;
          bf16x8 vf = *reinterpret_cast<bf16x8*>(
              &VtF[d * 72 + (((4 * kc + g) ^ (d >> 3)) << 3)]);
          o[dn] = mfma16(pf, vf, o[dn]);
        }
      }
      __builtin_amdgcn_s_setprio(0);
    };

    process(qfB, mB, lB, oB, &Pl[wid][1][0][0], qt0B, s == tB);
    if (s <= tA)
      process(qfA, mA, lA, oA, &Pl[wid][0][0][0], qt0A, s == tA);
  }

  // epilogue per tile
  auto epi = [&](float l_p, f32x4 (&o)[4], int qt0) {
    l_p += __shfl_xor(l_p, 16);
    l_p += __shfl_xor(l_p, 32);
    float linv = 1.f / l_p;
    float i0 = __shfl(linv, g * 4 + 0);
    float i1 = __shfl(linv, g * 4 + 1);
    float i2 = __shfl(linv, g * 4 + 2);
    float i3 = __shfl(linv, g * 4 + 3);
#pragma unroll
    for (int j = 0; j < 4; ++j) {
      float inv = j == 0 ? i0 : (j == 1 ? i1 : (j == 2 ? i2 : i3));
      int qrow = qt0 + g * 4 + j;
#pragma unroll
      for (int dn = 0; dn < 4; ++dn) {
        int d = dn * 16 + r;
        Y[((size_t)bidx * T_ + qrow) * C_ + h * HD_ + d] = (bf16)(o[dn][j] * inv);
      }
    }
  };
  epi(lA, oA, qt0A);
  epi(lB, oB, qt0B);
}

// ---------------------------------------------------------------- launch
extern "C" void kernel_launch(void* const* d_in, const int* in_sizes, int n_in,
                              void* d_out, int out_size, void* d_ws, size_t ws_size,
                              hipStream_t stream) {
  const float* x  = (const float*)d_in[0];
  const float* Wa = (const float*)d_in[1];
  const float* ba = (const float*)d_in[2];
  const float* Wp = (const float*)d_in[3];
  const float* bp = (const float*)d_in[4];
  float* out = (float*)d_out;

  char* ws = (char*)d_ws;
  size_t off = 0;
  auto alloc = [&](size_t bytes) {
    char* p = ws + off;
    off += (bytes + 255) & ~(size_t)255;
    return p;
  };
  bf16* xb   = (bf16*)alloc((size_t)B_ * T_ * C_ * 2);
  bf16* WaT  = (bf16*)alloc((size_t)C_ * 3 * C_ * 2);   // [3C][C]
  bf16* WpT  = (bf16*)alloc((size_t)C_ * C_ * 2);       // [C][C]
  bf16* Qb   = (bf16*)alloc((size_t)BH_ * T_ * HD_ * 2);
  bf16* Kb   = (bf16*)alloc((size_t)BH_ * T_ * HD_ * 2);
  bf16* Vb   = (bf16*)alloc((size_t)BH_ * T_ * HD_ * 2);
  bf16* Yb   = (bf16*)alloc((size_t)B_ * T_ * C_ * 2);

  const int M = B_ * T_;  // 8192

  cvt_kernel<<<(M * C_ / 4) / 256, 256, 0, stream>>>(x, xb, M * C_ / 4);
  wtr_kernel<<<dim3(C_ / 64, 3 * C_ / 64), 256, 0, stream>>>(Wa, WaT, C_, 3 * C_);
  wtr_kernel<<<dim3(C_ / 64, C_ / 64), 256, 0, stream>>>(Wp, WpT, C_, C_);

  gemm_mfma<0><<<dim3(3 * C_ / 128, M / 128), 256, 0, stream>>>(
      xb, WaT, ba, M, 3 * C_, C_, Qb, Kb, Vb, nullptr);

  attn_fwd<<<dim3(16, BH_), 256, 0, stream>>>(Qb, Kb, Vb, Yb);

  gemm_mfma<1><<<dim3(C_ / 128, M / 128), 256, 0, stream>>>(
      Yb, WpT, bp, M, C_, C_, nullptr, nullptr, nullptr, out);
}

// Round 11
// 241.586 us; speedup vs baseline: 1.1008x; 1.1008x over previous
//
#include <hip/hip_runtime.h>
#include <hip/hip_bf16.h>
#include <cstdint>

typedef __bf16 bf16;
typedef __bf16 bf16x4 __attribute__((ext_vector_type(4)));
typedef __bf16 bf16x8 __attribute__((ext_vector_type(8)));
typedef float f32x4 __attribute__((ext_vector_type(4)));

#define B_  4
#define T_  2048
#define C_  768
#define NH_ 12
#define HD_ 64
#define BH_ (B_ * NH_)

__device__ __forceinline__ f32x4 mfma16(bf16x8 a, bf16x8 b, f32x4 c) {
  return __builtin_amdgcn_mfma_f32_16x16x32_bf16(a, b, c, 0, 0, 0);
}

// async global->LDS, 16B per lane; lds dst must be wave-uniform base (HW adds lane*16)
__device__ __forceinline__ void gload16(const bf16* src, bf16* dst) {
  __builtin_amdgcn_global_load_lds(
      (const __attribute__((address_space(1))) unsigned int*)src,
      (__attribute__((address_space(3))) unsigned int*)dst, 16, 0, 0);
}

// ---------------------------------------------------------------- convert (x)
__global__ __launch_bounds__(256) void cvt_kernel(const float* __restrict__ in,
                                                  bf16* __restrict__ out, int n4) {
  int i = blockIdx.x * blockDim.x + threadIdx.x;
  if (i < n4) {
    float4 v = reinterpret_cast<const float4*>(in)[i];
    bf16x4 o;
    o[0] = (bf16)v.x; o[1] = (bf16)v.y; o[2] = (bf16)v.z; o[3] = (bf16)v.w;
    reinterpret_cast<bf16x4*>(out)[i] = o;
  }
}

// ------------------------------------------- weight transpose+convert: WT[n][k] = W[k][n]
__global__ __launch_bounds__(256) void wtr_kernel(const float* __restrict__ W,
                                                  bf16* __restrict__ WT, int K, int N) {
  __shared__ bf16 t[64][72];
  const int tid = threadIdx.x;
  const int k0 = blockIdx.x * 64, n0 = blockIdx.y * 64;
  {
    const int r = tid >> 2, cg = (tid & 3) * 16;
    const float* src = W + (size_t)(k0 + r) * N + n0 + cg;
    float4 a0 = reinterpret_cast<const float4*>(src)[0];
    float4 a1 = reinterpret_cast<const float4*>(src)[1];
    float4 a2 = reinterpret_cast<const float4*>(src)[2];
    float4 a3 = reinterpret_cast<const float4*>(src)[3];
    bf16x8 lo, hi;
    lo[0]=(bf16)a0.x; lo[1]=(bf16)a0.y; lo[2]=(bf16)a0.z; lo[3]=(bf16)a0.w;
    lo[4]=(bf16)a1.x; lo[5]=(bf16)a1.y; lo[6]=(bf16)a1.z; lo[7]=(bf16)a1.w;
    hi[0]=(bf16)a2.x; hi[1]=(bf16)a2.y; hi[2]=(bf16)a2.z; hi[3]=(bf16)a2.w;
    hi[4]=(bf16)a3.x; hi[5]=(bf16)a3.y; hi[6]=(bf16)a3.z; hi[7]=(bf16)a3.w;
    *reinterpret_cast<bf16x8*>(&t[r][cg]) = lo;
    *reinterpret_cast<bf16x8*>(&t[r][cg + 8]) = hi;
  }
  __syncthreads();
  {
    const int n = tid & 63, kg = (tid >> 6) * 16;
    bf16x8 o0, o1;
#pragma unroll
    for (int i = 0; i < 8; ++i) { o0[i] = t[kg + i][n]; o1[i] = t[kg + 8 + i][n]; }
    bf16* dst = WT + (size_t)(n0 + n) * K + k0 + kg;
    *reinterpret_cast<bf16x8*>(dst) = o0;
    *reinterpret_cast<bf16x8*>(dst + 8) = o1;
  }
}

// ---------------------------------------------------------------- GEMM (m97-style, BK=64)
// C[M,N] = A[M,K] @ B, BT is B transposed ([N][K]). Both bf16.
// EPI 0: scatter to Q/K/V bf16 (Q scaled by 0.125*log2e). EPI 1: fp32 out.
template <int EPI>
__global__ __launch_bounds__(256) void gemm_mfma(
    const bf16* __restrict__ A, const bf16* __restrict__ BT,
    const float* __restrict__ bias, int M, int N, int K,
    bf16* __restrict__ q, bf16* __restrict__ k_, bf16* __restrict__ v,
    float* __restrict__ out) {
  __shared__ bf16 AlF[128 * 64];   // [m][k] linear (global_load_lds dest)
  __shared__ bf16 BlF[128 * 64];   // [n][k] linear

  const int tid = threadIdx.x;
  const int wid = tid >> 6, lane = tid & 63;
  unsigned orig = blockIdx.y * gridDim.x + blockIdx.x;
  unsigned cpx = (gridDim.x * gridDim.y) >> 3;
  unsigned work = (orig & 7) * cpx + (orig >> 3);
  const int m0 = (work / gridDim.x) * 128, n0 = (work % gridDim.x) * 128;
  const int wm = (wid >> 1) * 64, wn = (wid & 1) * 64;
  const int r = lane & 15, g = lane >> 4;

  f32x4 acc[4][4] = {};

  const int l8 = lane >> 3;          // 0..7 row-within-issue
  const int c8 = (lane & 7) * 8;     // k-col group

  for (int k0 = 0; k0 < K; k0 += 64) {
    __syncthreads();
#pragma unroll
    for (int i = 0; i < 4; ++i) {
      int row = i * 32 + wid * 8 + l8;
      gload16(A  + (size_t)(m0 + row) * K + k0 + c8, AlF + (i * 32 + wid * 8) * 64);
      gload16(BT + (size_t)(n0 + row) * K + k0 + c8, BlF + (i * 32 + wid * 8) * 64);
    }
    __syncthreads();

#pragma unroll
    for (int kc = 0; kc < 2; ++kc) {
      bf16x8 bfr[4];
#pragma unroll
      for (int fn = 0; fn < 4; ++fn)
        bfr[fn] = *reinterpret_cast<bf16x8*>(&BlF[(wn + fn * 16 + r) * 64 + kc * 32 + g * 8]);
#pragma unroll
      for (int fm = 0; fm < 4; ++fm) {
        bf16x8 af = *reinterpret_cast<bf16x8*>(&AlF[(wm + fm * 16 + r) * 64 + kc * 32 + g * 8]);
#pragma unroll
        for (int fn = 0; fn < 4; ++fn)
          acc[fm][fn] = mfma16(af, bfr[fn], acc[fm][fn]);
      }
    }
  }

  // epilogue: C row = g*4+j, col = r  (verified m89/m91 layout)
#pragma unroll
  for (int fm = 0; fm < 4; ++fm)
#pragma unroll
    for (int fn = 0; fn < 4; ++fn)
#pragma unroll
      for (int j = 0; j < 4; ++j) {
        int m = m0 + wm + fm * 16 + g * 4 + j;
        int n = n0 + wn + fn * 16 + r;
        float val = acc[fm][fn][j] + bias[n];
        if (EPI == 0) {
          int b = m >> 11, t = m & 2047;
          bf16* dst; int c;
          if (n < 768)        { dst = q;  c = n;        val *= 0.180336881f; }  // 0.125*log2(e)
          else if (n < 1536)  { dst = k_; c = n - 768;  }
          else                { dst = v;  c = n - 1536; }
          int h = c >> 6, d = c & 63;
          dst[(((size_t)(b * NH_ + h)) * T_ + t) * HD_ + d] = (bf16)val;
        } else {
          out[(size_t)m * N + n] = val;
        }
      }
}

// ---------------------------------------------------------------- attention
// grid: (16, B*NH), XCD-swizzled. Block handles q-tiles {x, 31-x} sequentially
// (R8 structure) -> uniform 33 KV-steps. 4 waves/block, wave owns 16 q-rows.
// T14 async-stage: global loads for step s+1 issued before compute of step s.
// Swapped QK^T: lane owns q = qt0 + r. exp2-domain softmax, defer-max thr 8.
__global__ __launch_bounds__(256) void attn_fwd(
    const bf16* __restrict__ Q, const bf16* __restrict__ K,
    const bf16* __restrict__ V, bf16* __restrict__ Y) {
  __shared__ bf16 Kl[64][72];       // [kv][d]
  __shared__ bf16 VtF[64 * 72];     // swizzled [d][kv]
  __shared__ bf16 Pl[4][16][72];    // per-wave P buffer [qrow][kv]

  const int tid = threadIdx.x;
  const int wid = tid >> 6, lane = tid & 63;
  const int r = lane & 15, g = lane >> 4;

  // XCD swizzle: 768 blocks -> 96-work contiguous chunks per XCD (6 whole heads)
  unsigned orig = blockIdx.y * 16 + blockIdx.x;
  unsigned work = (orig & 7) * 96 + (orig >> 3);
  const int bx = work & 15;
  const int bh = work >> 4;
  const int bidx = bh / NH_, h = bh % NH_;

  const bf16* Qb = Q + (size_t)bh * T_ * HD_;
  const bf16* Kb = K + (size_t)bh * T_ * HD_;
  const bf16* Vb = V + (size_t)bh * T_ * HD_;

  const int krow = tid >> 3;          // 0..31
  const int kc8 = (tid & 7) * 8;

#pragma unroll
  for (int pass = 0; pass < 2; ++pass) {
    const int tile = pass ? 31 - bx : bx;
    const int qt0 = tile * 64 + wid * 16;

    // Q fragments straight from global (pre-scaled by 0.125*log2e)
    bf16x8 qf[2];
#pragma unroll
    for (int kc = 0; kc < 2; ++kc)
      qf[kc] = *reinterpret_cast<const bf16x8*>(
          Qb + (size_t)(qt0 + r) * HD_ + kc * 32 + g * 8);

    float m_st = -INFINITY;   // running max for q = qt0 + r (log2 domain)
    float l_p = 0.f;          // per-lane partial sum (this lane's 16 kv slots)
    f32x4 o[4] = {};

    const int nsteps = tile + 1;

    // prologue: load kv-tile 0 into regs
    bf16x8 kreg[2], vreg[2];
#pragma unroll
    for (int p = 0; p < 2; ++p) {
      int row = p * 32 + krow;
      kreg[p] = *reinterpret_cast<const bf16x8*>(Kb + (size_t)row * HD_ + kc8);
      vreg[p] = *reinterpret_cast<const bf16x8*>(Vb + (size_t)row * HD_ + kc8);
    }

    for (int s = 0; s < nsteps; ++s) {
      const int kv0 = s * 64;
      // write staged regs -> LDS (prev readers done via trailing barrier)
#pragma unroll
      for (int p = 0; p < 2; ++p) {
        int row = p * 32 + krow;
        *reinterpret_cast<bf16x8*>(&Kl[row][kc8]) = kreg[p];
        int xorb = (((row >> 3) ^ (tid & 7)) << 3) + (row & 7);  // per-row swizzle
#pragma unroll
        for (int j = 0; j < 8; ++j) VtF[(kc8 + j) * 72 + xorb] = vreg[p][j];
      }
      __syncthreads();

      // T14: issue next tile's global loads now; they fly under compute
      if (s + 1 < nsteps) {
        const int kvn = kv0 + 64;
#pragma unroll
        for (int p = 0; p < 2; ++p) {
          int row = kvn + p * 32 + krow;
          kreg[p] = *reinterpret_cast<const bf16x8*>(Kb + (size_t)row * HD_ + kc8);
          vreg[p] = *reinterpret_cast<const bf16x8*>(Vb + (size_t)row * HD_ + kc8);
        }
      }

      // S^T = K @ Q^T  (64 kv x 16 q): s4[cb] row = kv = cb*16+g*4+j, col = q = r
      f32x4 s4[4] = {};
      __builtin_amdgcn_s_setprio(1);
#pragma unroll
      for (int cb = 0; cb < 4; ++cb)
#pragma unroll
        for (int kc = 0; kc < 2; ++kc) {
          bf16x8 kf = *reinterpret_cast<bf16x8*>(&Kl[cb * 16 + r][kc * 32 + g * 8]);
          s4[cb] = mfma16(kf, qf[kc], s4[cb]);
        }
      __builtin_amdgcn_s_setprio(0);

      if (s == tile) {  // diagonal block: causal mask (kv > q)
#pragma unroll
        for (int cb = 0; cb < 4; ++cb)
#pragma unroll
          for (int j = 0; j < 4; ++j)
            if (kv0 + cb * 16 + g * 4 + j > qt0 + r) s4[cb][j] = -INFINITY;
      }

      // lane-local softmax for q = qt0 + r (16 kv here; 64 across 4 g-lanes)
      float pmax = fmaxf(
          fmaxf(fmaxf(fmaxf(s4[0][0], s4[0][1]), fmaxf(s4[0][2], s4[0][3])),
                fmaxf(fmaxf(s4[1][0], s4[1][1]), fmaxf(s4[1][2], s4[1][3]))),
          fmaxf(fmaxf(fmaxf(s4[2][0], s4[2][1]), fmaxf(s4[2][2], s4[2][3])),
                fmaxf(fmaxf(s4[3][0], s4[3][1]), fmaxf(s4[3][2], s4[3][3]))));
      pmax = fmaxf(pmax, __shfl_xor(pmax, 16));
      pmax = fmaxf(pmax, __shfl_xor(pmax, 32));

      if (!__all(pmax - m_st <= 8.0f)) {   // defer-max: rescale only on real growth
        float sc = exp2f(m_st - pmax);
        m_st = pmax;
        l_p *= sc;
        float sc0 = __shfl(sc, g * 4 + 0);
        float sc1 = __shfl(sc, g * 4 + 1);
        float sc2 = __shfl(sc, g * 4 + 2);
        float sc3 = __shfl(sc, g * 4 + 3);
#pragma unroll
        for (int dn = 0; dn < 4; ++dn) {
          o[dn][0] *= sc0; o[dn][1] *= sc1; o[dn][2] *= sc2; o[dn][3] *= sc3;
        }
      }

      float sum = 0.f;
#pragma unroll
      for (int cb = 0; cb < 4; ++cb) {
        bf16x4 pw;
#pragma unroll
        for (int j = 0; j < 4; ++j) {
          float pv = exp2f(s4[cb][j] - m_st);
          sum += pv;
          pw[j] = (bf16)pv;
        }
        *reinterpret_cast<bf16x4*>(&Pl[wid][r][cb * 16 + g * 4]) = pw;
      }
      l_p += sum;

      // O += P @ V  (A-frag: P[q=r][kv], B-frag: Vt[d][kv])
      __builtin_amdgcn_s_setprio(1);
#pragma unroll
      for (int kc = 0; kc < 2; ++kc) {
        bf16x8 pf = *reinterpret_cast<bf16x8*>(&Pl[wid][r][kc * 32 + g * 8]);
#pragma unroll
        for (int dn = 0; dn < 4; ++dn) {
          int d = dn * 16 + r;
          bf16x8 vf = *reinterpret_cast<bf16x8*>(
              &VtF[d * 72 + (((4 * kc + g) ^ (d >> 3)) << 3)]);
          o[dn] = mfma16(pf, vf, o[dn]);
        }
      }
      __builtin_amdgcn_s_setprio(0);
      __syncthreads();
    }

    // final l reduce (across the 4 g-lanes of each r), then broadcast inverses
    l_p += __shfl_xor(l_p, 16);
    l_p += __shfl_xor(l_p, 32);
    float linv = 1.f / l_p;
    float i0 = __shfl(linv, g * 4 + 0);
    float i1 = __shfl(linv, g * 4 + 1);
    float i2 = __shfl(linv, g * 4 + 2);
    float i3 = __shfl(linv, g * 4 + 3);

    // write y bf16 in (B,T,C) layout; O row = q = g*4+j, col = d = dn*16+r
#pragma unroll
    for (int j = 0; j < 4; ++j) {
      float inv = j == 0 ? i0 : (j == 1 ? i1 : (j == 2 ? i2 : i3));
      int qrow = qt0 + g * 4 + j;
#pragma unroll
      for (int dn = 0; dn < 4; ++dn) {
        int d = dn * 16 + r;
        Y[((size_t)bidx * T_ + qrow) * C_ + h * HD_ + d] = (bf16)(o[dn][j] * inv);
      }
    }
  }
}

// ---------------------------------------------------------------- launch
extern "C" void kernel_launch(void* const* d_in, const int* in_sizes, int n_in,
                              void* d_out, int out_size, void* d_ws, size_t ws_size,
                              hipStream_t stream) {
  const float* x  = (const float*)d_in[0];
  const float* Wa = (const float*)d_in[1];
  const float* ba = (const float*)d_in[2];
  const float* Wp = (const float*)d_in[3];
  const float* bp = (const float*)d_in[4];
  float* out = (float*)d_out;

  char* ws = (char*)d_ws;
  size_t off = 0;
  auto alloc = [&](size_t bytes) {
    char* p = ws + off;
    off += (bytes + 255) & ~(size_t)255;
    return p;
  };
  bf16* xb   = (bf16*)alloc((size_t)B_ * T_ * C_ * 2);
  bf16* WaT  = (bf16*)alloc((size_t)C_ * 3 * C_ * 2);   // [3C][C]
  bf16* WpT  = (bf16*)alloc((size_t)C_ * C_ * 2);       // [C][C]
  bf16* Qb   = (bf16*)alloc((size_t)BH_ * T_ * HD_ * 2);
  bf16* Kb   = (bf16*)alloc((size_t)BH_ * T_ * HD_ * 2);
  bf16* Vb   = (bf16*)alloc((size_t)BH_ * T_ * HD_ * 2);
  bf16* Yb   = (bf16*)alloc((size_t)B_ * T_ * C_ * 2);

  const int M = B_ * T_;  // 8192

  cvt_kernel<<<(M * C_ / 4) / 256, 256, 0, stream>>>(x, xb, M * C_ / 4);
  wtr_kernel<<<dim3(C_ / 64, 3 * C_ / 64), 256, 0, stream>>>(Wa, WaT, C_, 3 * C_);
  wtr_kernel<<<dim3(C_ / 64, C_ / 64), 256, 0, stream>>>(Wp, WpT, C_, C_);

  gemm_mfma<0><<<dim3(3 * C_ / 128, M / 128), 256, 0, stream>>>(
      xb, WaT, ba, M, 3 * C_, C_, Qb, Kb, Vb, nullptr);

  attn_fwd<<<dim3(16, BH_), 256, 0, stream>>>(Qb, Kb, Vb, Yb);

  gemm_mfma<1><<<dim3(C_ / 128, M / 128), 256, 0, stream>>>(
      Yb, WpT, bp, M, C_, C_, nullptr, nullptr, nullptr, out);
}

// Round 12
// 237.557 us; speedup vs baseline: 1.1195x; 1.0170x over previous
//
#include <hip/hip_runtime.h>
#include <hip/hip_bf16.h>
#include <cstdint>

typedef __bf16 bf16;
typedef __bf16 bf16x4 __attribute__((ext_vector_type(4)));
typedef __bf16 bf16x8 __attribute__((ext_vector_type(8)));
typedef float f32x4 __attribute__((ext_vector_type(4)));

#define B_  4
#define T_  2048
#define C_  768
#define NH_ 12
#define HD_ 64
#define BH_ (B_ * NH_)

__device__ __forceinline__ f32x4 mfma16(bf16x8 a, bf16x8 b, f32x4 c) {
  return __builtin_amdgcn_mfma_f32_16x16x32_bf16(a, b, c, 0, 0, 0);
}

// async global->LDS, 16B per lane; lds dst must be wave-uniform base (HW adds lane*16)
__device__ __forceinline__ void gload16(const bf16* src, bf16* dst) {
  __builtin_amdgcn_global_load_lds(
      (const __attribute__((address_space(1))) unsigned int*)src,
      (__attribute__((address_space(3))) unsigned int*)dst, 16, 0, 0);
}

// ---------------------------------------------------------------- convert (x)
__global__ __launch_bounds__(256) void cvt_kernel(const float* __restrict__ in,
                                                  bf16* __restrict__ out, int n4) {
  int i = blockIdx.x * blockDim.x + threadIdx.x;
  if (i < n4) {
    float4 v = reinterpret_cast<const float4*>(in)[i];
    bf16x4 o;
    o[0] = (bf16)v.x; o[1] = (bf16)v.y; o[2] = (bf16)v.z; o[3] = (bf16)v.w;
    reinterpret_cast<bf16x4*>(out)[i] = o;
  }
}

// ------------------------------------------- weight transpose+convert: WT[n][k] = W[k][n]
__global__ __launch_bounds__(256) void wtr_kernel(const float* __restrict__ W,
                                                  bf16* __restrict__ WT, int K, int N) {
  __shared__ bf16 t[64][72];
  const int tid = threadIdx.x;
  const int k0 = blockIdx.x * 64, n0 = blockIdx.y * 64;
  {
    const int r = tid >> 2, cg = (tid & 3) * 16;
    const float* src = W + (size_t)(k0 + r) * N + n0 + cg;
    float4 a0 = reinterpret_cast<const float4*>(src)[0];
    float4 a1 = reinterpret_cast<const float4*>(src)[1];
    float4 a2 = reinterpret_cast<const float4*>(src)[2];
    float4 a3 = reinterpret_cast<const float4*>(src)[3];
    bf16x8 lo, hi;
    lo[0]=(bf16)a0.x; lo[1]=(bf16)a0.y; lo[2]=(bf16)a0.z; lo[3]=(bf16)a0.w;
    lo[4]=(bf16)a1.x; lo[5]=(bf16)a1.y; lo[6]=(bf16)a1.z; lo[7]=(bf16)a1.w;
    hi[0]=(bf16)a2.x; hi[1]=(bf16)a2.y; hi[2]=(bf16)a2.z; hi[3]=(bf16)a2.w;
    hi[4]=(bf16)a3.x; hi[5]=(bf16)a3.y; hi[6]=(bf16)a3.z; hi[7]=(bf16)a3.w;
    *reinterpret_cast<bf16x8*>(&t[r][cg]) = lo;
    *reinterpret_cast<bf16x8*>(&t[r][cg + 8]) = hi;
  }
  __syncthreads();
  {
    const int n = tid & 63, kg = (tid >> 6) * 16;
    bf16x8 o0, o1;
#pragma unroll
    for (int i = 0; i < 8; ++i) { o0[i] = t[kg + i][n]; o1[i] = t[kg + 8 + i][n]; }
    bf16* dst = WT + (size_t)(n0 + n) * K + k0 + kg;
    *reinterpret_cast<bf16x8*>(dst) = o0;
    *reinterpret_cast<bf16x8*>(dst + 8) = o1;
  }
}

// ---------------------------------------------------------------- GEMM (2-phase dbuf, BK=32)
// C[M,N] = A[M,K] @ B, BT is B transposed ([N][K]). Both bf16.
// Double-buffered LDS; next tile's global_load_lds issued BEFORE current compute;
// one __syncthreads per K-step (its vmcnt(0)+lgkmcnt(0) drain IS the pipeline wait).
// EPI 0: scatter to Q/K/V bf16 (Q scaled by 0.125*log2e). EPI 1: fp32 out.
template <int EPI>
__global__ __launch_bounds__(256) void gemm_mfma(
    const bf16* __restrict__ A, const bf16* __restrict__ BT,
    const float* __restrict__ bias, int M, int N, int K,
    bf16* __restrict__ q, bf16* __restrict__ k_, bf16* __restrict__ v,
    float* __restrict__ out) {
  __shared__ bf16 AlF[2][128 * 32];   // [buf][m][k] linear (global_load_lds dest)
  __shared__ bf16 BlF[2][128 * 32];   // [buf][n][k] linear

  const int tid = threadIdx.x;
  const int wid = tid >> 6, lane = tid & 63;
  unsigned orig = blockIdx.y * gridDim.x + blockIdx.x;
  unsigned cpx = (gridDim.x * gridDim.y) >> 3;
  unsigned work = (orig & 7) * cpx + (orig >> 3);
  const int m0 = (work / gridDim.x) * 128, n0 = (work % gridDim.x) * 128;
  const int wm = (wid >> 1) * 64, wn = (wid & 1) * 64;
  const int r = lane & 15, g = lane >> 4;

  f32x4 acc[4][4] = {};

  const int srow = tid >> 2;          // 0..63 (pass c adds 64)
  const int scol = (tid & 3) * 8;

  // prologue: stage k-tile 0 into buf 0
#pragma unroll
  for (int c = 0; c < 2; ++c) {
    gload16(A  + (size_t)(m0 + c * 64 + srow) * K + scol, &AlF[0][c * 2048 + wid * 512]);
    gload16(BT + (size_t)(n0 + c * 64 + srow) * K + scol, &BlF[0][c * 2048 + wid * 512]);
  }

  int cur = 0;
  for (int k0 = 0; k0 < K; k0 += 32) {
    __syncthreads();   // drains vmcnt(0): buf[cur] ready; prev ds_reads done

    if (k0 + 32 < K) {  // issue next tile into buf[cur^1]; flies under compute
#pragma unroll
      for (int c = 0; c < 2; ++c) {
        gload16(A  + (size_t)(m0 + c * 64 + srow) * K + k0 + 32 + scol,
                &AlF[cur ^ 1][c * 2048 + wid * 512]);
        gload16(BT + (size_t)(n0 + c * 64 + srow) * K + k0 + 32 + scol,
                &BlF[cur ^ 1][c * 2048 + wid * 512]);
      }
    }

    bf16x8 af[4], bfr[4];
#pragma unroll
    for (int fm = 0; fm < 4; ++fm)
      af[fm] = *reinterpret_cast<bf16x8*>(&AlF[cur][(wm + fm * 16 + r) * 32 + g * 8]);
#pragma unroll
    for (int fn = 0; fn < 4; ++fn)
      bfr[fn] = *reinterpret_cast<bf16x8*>(&BlF[cur][(wn + fn * 16 + r) * 32 + g * 8]);
    __builtin_amdgcn_s_setprio(1);
#pragma unroll
    for (int fm = 0; fm < 4; ++fm)
#pragma unroll
      for (int fn = 0; fn < 4; ++fn)
        acc[fm][fn] = mfma16(af[fm], bfr[fn], acc[fm][fn]);
    __builtin_amdgcn_s_setprio(0);
    cur ^= 1;
  }

  // epilogue: C row = g*4+j, col = r  (verified m89/m91 layout)
#pragma unroll
  for (int fm = 0; fm < 4; ++fm)
#pragma unroll
    for (int fn = 0; fn < 4; ++fn)
#pragma unroll
      for (int j = 0; j < 4; ++j) {
        int m = m0 + wm + fm * 16 + g * 4 + j;
        int n = n0 + wn + fn * 16 + r;
        float val = acc[fm][fn][j] + bias[n];
        if (EPI == 0) {
          int b = m >> 11, t = m & 2047;
          bf16* dst; int c;
          if (n < 768)        { dst = q;  c = n;        val *= 0.180336881f; }  // 0.125*log2(e)
          else if (n < 1536)  { dst = k_; c = n - 768;  }
          else                { dst = v;  c = n - 1536; }
          int h = c >> 6, d = c & 63;
          dst[(((size_t)(b * NH_ + h)) * T_ + t) * HD_ + d] = (bf16)val;
        } else {
          out[(size_t)m * N + n] = val;
        }
      }
}

// ---------------------------------------------------------------- attention
// grid: (16, B*NH), XCD-swizzled. Block handles q-tiles {x, 31-x} sequentially
// (R8 structure) -> uniform 33 KV-steps. 4 waves/block, wave owns 16 q-rows.
// T14 async-stage: global loads for step s+1 issued before compute of step s.
// Swapped QK^T: lane owns q = qt0 + r. exp2-domain softmax, defer-max thr 8.
__global__ __launch_bounds__(256) void attn_fwd(
    const bf16* __restrict__ Q, const bf16* __restrict__ K,
    const bf16* __restrict__ V, bf16* __restrict__ Y) {
  __shared__ bf16 Kl[64][72];       // [kv][d]
  __shared__ bf16 VtF[64 * 72];     // swizzled [d][kv]
  __shared__ bf16 Pl[4][16][72];    // per-wave P buffer [qrow][kv]

  const int tid = threadIdx.x;
  const int wid = tid >> 6, lane = tid & 63;
  const int r = lane & 15, g = lane >> 4;

  // XCD swizzle: 768 blocks -> 96-work contiguous chunks per XCD (6 whole heads)
  unsigned orig = blockIdx.y * 16 + blockIdx.x;
  unsigned work = (orig & 7) * 96 + (orig >> 3);
  const int bx = work & 15;
  const int bh = work >> 4;
  const int bidx = bh / NH_, h = bh % NH_;

  const bf16* Qb = Q + (size_t)bh * T_ * HD_;
  const bf16* Kb = K + (size_t)bh * T_ * HD_;
  const bf16* Vb = V + (size_t)bh * T_ * HD_;

  const int krow = tid >> 3;          // 0..31
  const int kc8 = (tid & 7) * 8;

#pragma unroll
  for (int pass = 0; pass < 2; ++pass) {
    const int tile = pass ? 31 - bx : bx;
    const int qt0 = tile * 64 + wid * 16;

    // Q fragments straight from global (pre-scaled by 0.125*log2e)
    bf16x8 qf[2];
#pragma unroll
    for (int kc = 0; kc < 2; ++kc)
      qf[kc] = *reinterpret_cast<const bf16x8*>(
          Qb + (size_t)(qt0 + r) * HD_ + kc * 32 + g * 8);

    float m_st = -INFINITY;   // running max for q = qt0 + r (log2 domain)
    float l_p = 0.f;          // per-lane partial sum (this lane's 16 kv slots)
    f32x4 o[4] = {};

    const int nsteps = tile + 1;

    // prologue: load kv-tile 0 into regs
    bf16x8 kreg[2], vreg[2];
#pragma unroll
    for (int p = 0; p < 2; ++p) {
      int row = p * 32 + krow;
      kreg[p] = *reinterpret_cast<const bf16x8*>(Kb + (size_t)row * HD_ + kc8);
      vreg[p] = *reinterpret_cast<const bf16x8*>(Vb + (size_t)row * HD_ + kc8);
    }

    for (int s = 0; s < nsteps; ++s) {
      const int kv0 = s * 64;
      // write staged regs -> LDS (prev readers done via trailing barrier)
#pragma unroll
      for (int p = 0; p < 2; ++p) {
        int row = p * 32 + krow;
        *reinterpret_cast<bf16x8*>(&Kl[row][kc8]) = kreg[p];
        int xorb = (((row >> 3) ^ (tid & 7)) << 3) + (row & 7);  // per-row swizzle
#pragma unroll
        for (int j = 0; j < 8; ++j) VtF[(kc8 + j) * 72 + xorb] = vreg[p][j];
      }
      __syncthreads();

      // T14: issue next tile's global loads now; they fly under compute
      if (s + 1 < nsteps) {
        const int kvn = kv0 + 64;
#pragma unroll
        for (int p = 0; p < 2; ++p) {
          int row = kvn + p * 32 + krow;
          kreg[p] = *reinterpret_cast<const bf16x8*>(Kb + (size_t)row * HD_ + kc8);
          vreg[p] = *reinterpret_cast<const bf16x8*>(Vb + (size_t)row * HD_ + kc8);
        }
      }

      // S^T = K @ Q^T  (64 kv x 16 q): s4[cb] row = kv = cb*16+g*4+j, col = q = r
      f32x4 s4[4] = {};
      __builtin_amdgcn_s_setprio(1);
#pragma unroll
      for (int cb = 0; cb < 4; ++cb)
#pragma unroll
        for (int kc = 0; kc < 2; ++kc) {
          bf16x8 kf = *reinterpret_cast<bf16x8*>(&Kl[cb * 16 + r][kc * 32 + g * 8]);
          s4[cb] = mfma16(kf, qf[kc], s4[cb]);
        }
      __builtin_amdgcn_s_setprio(0);

      if (s == tile) {  // diagonal block: causal mask (kv > q)
#pragma unroll
        for (int cb = 0; cb < 4; ++cb)
#pragma unroll
          for (int j = 0; j < 4; ++j)
            if (kv0 + cb * 16 + g * 4 + j > qt0 + r) s4[cb][j] = -INFINITY;
      }

      // lane-local softmax for q = qt0 + r (16 kv here; 64 across 4 g-lanes)
      float pmax = fmaxf(
          fmaxf(fmaxf(fmaxf(s4[0][0], s4[0][1]), fmaxf(s4[0][2], s4[0][3])),
                fmaxf(fmaxf(s4[1][0], s4[1][1]), fmaxf(s4[1][2], s4[1][3]))),
          fmaxf(fmaxf(fmaxf(s4[2][0], s4[2][1]), fmaxf(s4[2][2], s4[2][3])),
                fmaxf(fmaxf(s4[3][0], s4[3][1]), fmaxf(s4[3][2], s4[3][3]))));
      pmax = fmaxf(pmax, __shfl_xor(pmax, 16));
      pmax = fmaxf(pmax, __shfl_xor(pmax, 32));

      if (!__all(pmax - m_st <= 8.0f)) {   // defer-max: rescale only on real growth
        float sc = exp2f(m_st - pmax);
        m_st = pmax;
        l_p *= sc;
        float sc0 = __shfl(sc, g * 4 + 0);
        float sc1 = __shfl(sc, g * 4 + 1);
        float sc2 = __shfl(sc, g * 4 + 2);
        float sc3 = __shfl(sc, g * 4 + 3);
#pragma unroll
        for (int dn = 0; dn < 4; ++dn) {
          o[dn][0] *= sc0; o[dn][1] *= sc1; o[dn][2] *= sc2; o[dn][3] *= sc3;
        }
      }

      float sum = 0.f;
#pragma unroll
      for (int cb = 0; cb < 4; ++cb) {
        bf16x4 pw;
#pragma unroll
        for (int j = 0; j < 4; ++j) {
          float pv = exp2f(s4[cb][j] - m_st);
          sum += pv;
          pw[j] = (bf16)pv;
        }
        *reinterpret_cast<bf16x4*>(&Pl[wid][r][cb * 16 + g * 4]) = pw;
      }
      l_p += sum;

      // O += P @ V  (A-frag: P[q=r][kv], B-frag: Vt[d][kv])
      __builtin_amdgcn_s_setprio(1);
#pragma unroll
      for (int kc = 0; kc < 2; ++kc) {
        bf16x8 pf = *reinterpret_cast<bf16x8*>(&Pl[wid][r][kc * 32 + g * 8]);
#pragma unroll
        for (int dn = 0; dn < 4; ++dn) {
          int d = dn * 16 + r;
          bf16x8 vf = *reinterpret_cast<bf16x8*>(
              &VtF[d * 72 + (((4 * kc + g) ^ (d >> 3)) << 3)]);
          o[dn] = mfma16(pf, vf, o[dn]);
        }
      }
      __builtin_amdgcn_s_setprio(0);
      __syncthreads();
    }

    // final l reduce (across the 4 g-lanes of each r), then broadcast inverses
    l_p += __shfl_xor(l_p, 16);
    l_p += __shfl_xor(l_p, 32);
    float linv = 1.f / l_p;
    float i0 = __shfl(linv, g * 4 + 0);
    float i1 = __shfl(linv, g * 4 + 1);
    float i2 = __shfl(linv, g * 4 + 2);
    float i3 = __shfl(linv, g * 4 + 3);

    // write y bf16 in (B,T,C) layout; O row = q = g*4+j, col = d = dn*16+r
#pragma unroll
    for (int j = 0; j < 4; ++j) {
      float inv = j == 0 ? i0 : (j == 1 ? i1 : (j == 2 ? i2 : i3));
      int qrow = qt0 + g * 4 + j;
#pragma unroll
      for (int dn = 0; dn < 4; ++dn) {
        int d = dn * 16 + r;
        Y[((size_t)bidx * T_ + qrow) * C_ + h * HD_ + d] = (bf16)(o[dn][j] * inv);
      }
    }
  }
}

// ---------------------------------------------------------------- launch
extern "C" void kernel_launch(void* const* d_in, const int* in_sizes, int n_in,
                              void* d_out, int out_size, void* d_ws, size_t ws_size,
                              hipStream_t stream) {
  const float* x  = (const float*)d_in[0];
  const float* Wa = (const float*)d_in[1];
  const float* ba = (const float*)d_in[2];
  const float* Wp = (const float*)d_in[3];
  const float* bp = (const float*)d_in[4];
  float* out = (float*)d_out;

  char* ws = (char*)d_ws;
  size_t off = 0;
  auto alloc = [&](size_t bytes) {
    char* p = ws + off;
    off += (bytes + 255) & ~(size_t)255;
    return p;
  };
  bf16* xb   = (bf16*)alloc((size_t)B_ * T_ * C_ * 2);
  bf16* WaT  = (bf16*)alloc((size_t)C_ * 3 * C_ * 2);   // [3C][C]
  bf16* WpT  = (bf16*)alloc((size_t)C_ * C_ * 2);       // [C][C]
  bf16* Qb   = (bf16*)alloc((size_t)BH_ * T_ * HD_ * 2);
  bf16* Kb   = (bf16*)alloc((size_t)BH_ * T_ * HD_ * 2);
  bf16* Vb   = (bf16*)alloc((size_t)BH_ * T_ * HD_ * 2);
  bf16* Yb   = (bf16*)alloc((size_t)B_ * T_ * C_ * 2);

  const int M = B_ * T_;  // 8192

  cvt_kernel<<<(M * C_ / 4) / 256, 256, 0, stream>>>(x, xb, M * C_ / 4);
  wtr_kernel<<<dim3(C_ / 64, 3 * C_ / 64), 256, 0, stream>>>(Wa, WaT, C_, 3 * C_);
  wtr_kernel<<<dim3(C_ / 64, C_ / 64), 256, 0, stream>>>(Wp, WpT, C_, C_);

  gemm_mfma<0><<<dim3(3 * C_ / 128, M / 128), 256, 0, stream>>>(
      xb, WaT, ba, M, 3 * C_, C_, Qb, Kb, Vb, nullptr);

  attn_fwd<<<dim3(16, BH_), 256, 0, stream>>>(Qb, Kb, Vb, Yb);

  gemm_mfma<1><<<dim3(C_ / 128, M / 128), 256, 0, stream>>>(
      Yb, WpT, bp, M, C_, C_, nullptr, nullptr, nullptr, out);
}